// Round 4
// baseline (6624.231 us; speedup 1.0000x reference)
//
#include <hip/hip_runtime.h>

#define EDIM 512
#define NL 4
#define NB 32
#define SEQ 48
#define SDD 48
#define DVV 16000
#define NBLK 128
#define NTHR 1024
#define NTILES (DVV/16)   // 1000 vocab tiles of 16

// ---- ws layout (byte offsets) ----
#define BAR_OFF 0
#define WCE_OFF 256
#define H3F_OFF 512                                  // [32][512] f32 top-layer h (for attention)
#define HBF_OFF (H3F_OFF + NB*EDIM*4)                // [2][4][32][512] bf16 h (parity-buffered)
#define ZERO_BYTES (HBF_OFF + 2*NL*NB*EDIM*2)        // memset 0 .. here (bar + hbf zeros)
#define DEB_OFF ZERO_BYTES                           // [32][512] bf16 decoder LSTM input
#define CWS_OFF (DEB_OFF + NB*EDIM*2)                // [4][32][512] f32 c handoff enc->dec
#define UPO_OFF (CWS_OFF + (size_t)NL*NB*EDIM*4)     // [32][48][512] bf16 encoder outputs
#define EXB_OFF (UPO_OFF + (size_t)NB*SEQ*EDIM*2)    // [32][48][512] bf16 encoder embeddings
#define CEP_OFF (EXB_OFF + (size_t)NB*SEQ*EDIM*2)    // [32][1000][4] f32 logits partials
#define WI1_OFF (CEP_OFF + (size_t)NB*NTILES*4*4)
#define WH1_OFF (WI1_OFF + (size_t)NL*4*EDIM*EDIM*2)
#define WI2_OFF (WH1_OFF + (size_t)NL*4*EDIM*EDIM*2)
#define WH2_OFF (WI2_OFF + (size_t)NL*4*EDIM*EDIM*2)
#define W3B_OFF (WH2_OFF + (size_t)NL*4*EDIM*EDIM*2)
#define W2T_OFF (W3B_OFF + (size_t)DVV*EDIM*2)       // [560][512] bf16 W2 transposed
#define BS1_OFF (W2T_OFF + (size_t)560*EDIM*2)       // [4][2048] f32 bih1+bhh1
#define BS2_OFF (BS1_OFF + (size_t)NL*4*EDIM*4)      // [4][2048] f32 bih2+bhh2

typedef __bf16 bf16x8 __attribute__((ext_vector_type(8)));
typedef float floatx4 __attribute__((ext_vector_type(4)));
typedef unsigned int uint4e __attribute__((ext_vector_type(4)));
typedef unsigned short ushort4e __attribute__((ext_vector_type(4)));

struct Params {
  const int *etok, *elen, *dtok;
  const float *emb2;
  const float *W1, *b1, *b2;
  const float *b3;
  float* out;
  char* ws;
};

__device__ __forceinline__ float wred_sum(float v) {
#pragma unroll
  for (int i = 32; i > 0; i >>= 1) v += __shfl_xor(v, i, 64);
  return v;
}
__device__ __forceinline__ float wred_max(float v) {
#pragma unroll
  for (int i = 32; i > 0; i >>= 1) v = fmaxf(v, __shfl_xor(v, i, 64));
  return v;
}
__device__ __forceinline__ float sigm(float x) { return 1.f / (1.f + __expf(-x)); }
__device__ __forceinline__ float tanh_f(float x) { return 1.f - 2.f / (__expf(2.f * x) + 1.f); }
__device__ __forceinline__ unsigned short f2bf(float f) {  // RNE fp32->bf16
  unsigned int u = __float_as_uint(f);
  return (unsigned short)((u + 0x7fffu + ((u >> 16) & 1u)) >> 16);
}
__device__ __forceinline__ bf16x8 ld_bf8(const unsigned short* p) {
  return __builtin_bit_cast(bf16x8, *(const uint4e*)p);
}
__device__ __forceinline__ floatx4 mfma16(bf16x8 a, bf16x8 b, floatx4 c) {
  return __builtin_amdgcn_mfma_f32_16x16x32_bf16(a, b, c, 0, 0, 0);
}

// ===== LLC-coherent (bypass L1+L2) access helpers: sc0 sc1 =====
__device__ __forceinline__ uint4e ld_b128_llc(const void* p) {
  uint4e v;
  asm volatile("global_load_dwordx4 %0, %1, off sc0 sc1\n\ts_waitcnt vmcnt(0)"
               : "=&v"(v) : "v"(p) : "memory");
  return v;
}
__device__ __forceinline__ unsigned int ld_b32_llc(const void* p) {
  unsigned int v;
  asm volatile("global_load_dword %0, %1, off sc0 sc1\n\ts_waitcnt vmcnt(0)"
               : "=&v"(v) : "v"(p) : "memory");
  return v;
}
__device__ __forceinline__ unsigned short ld_b16_llc(const void* p) {
  unsigned short v;
  asm volatile("global_load_ushort %0, %1, off sc0 sc1\n\ts_waitcnt vmcnt(0)"
               : "=&v"(v) : "v"(p) : "memory");
  return v;
}
__device__ __forceinline__ void st_b32_llc(void* p, unsigned int v) {
  asm volatile("global_store_dword %0, %1, off sc0 sc1" :: "v"(p), "v"(v) : "memory");
}
__device__ __forceinline__ void st_b16_llc(void* p, unsigned short v) {
  asm volatile("global_store_short %0, %1, off sc0 sc1" :: "v"(p), "v"(v) : "memory");
}
__device__ __forceinline__ void st_b128_llc(void* p, uint4e v) {
  asm volatile("global_store_dwordx4 %0, %1, off sc0 sc1" :: "v"(p), "v"(v) : "memory");
}
// 8 loads (two rows x 4 chunks, 64B chunk stride), ONE waitcnt.
__device__ __forceinline__ void ld8_llc(const void* p0, const void* p1,
                                        uint4e* o0, uint4e* o1) {
  asm volatile(
      "global_load_dwordx4 %0, %8, off sc0 sc1\n\t"
      "global_load_dwordx4 %1, %8, off offset:64 sc0 sc1\n\t"
      "global_load_dwordx4 %2, %8, off offset:128 sc0 sc1\n\t"
      "global_load_dwordx4 %3, %8, off offset:192 sc0 sc1\n\t"
      "global_load_dwordx4 %4, %9, off sc0 sc1\n\t"
      "global_load_dwordx4 %5, %9, off offset:64 sc0 sc1\n\t"
      "global_load_dwordx4 %6, %9, off offset:128 sc0 sc1\n\t"
      "global_load_dwordx4 %7, %9, off offset:192 sc0 sc1\n\t"
      "s_waitcnt vmcnt(0)"
      : "=&v"(o0[0]), "=&v"(o0[1]), "=&v"(o0[2]), "=&v"(o0[3]),
        "=&v"(o1[0]), "=&v"(o1[1]), "=&v"(o1[2]), "=&v"(o1[3])
      : "v"(p0), "v"(p1) : "memory");
}

// grid barrier: RELEASE add (wbl2 on clean L2 = cheap), RELAXED spin, NO acquire ->
// no buffer_inv -> weights stay L2-resident across all phases. All cross-block
// state goes through the sc1 helpers above (coherent at LLC).
__device__ __forceinline__ void gsync(int* bar, int ph) {
  __syncthreads();  // drains vmcnt: all sc1 stores visible at LLC
  if (threadIdx.x == 0) {
    __hip_atomic_fetch_add(&bar[0], 1, __ATOMIC_RELEASE, __HIP_MEMORY_SCOPE_AGENT);
    const int target = ph * NBLK;
    while (__hip_atomic_load(&bar[0], __ATOMIC_RELAXED, __HIP_MEMORY_SCOPE_AGENT) < target)
      __builtin_amdgcn_s_sleep(8);
  }
  __syncthreads();
}

// One 4-gate LSTM GEMM slice. Weights: cached loads. x/h state: sc1 batched loads.
__device__ void gemm4g(const unsigned short* Wi, const unsigned short* Wh,
                       const unsigned short* xsrc, int xstr, const unsigned short* hsrc,
                       int et, int tid, float* parts) {
  const int wid = tid >> 6, lane = tid & 63, ln = lane & 15, kq = lane >> 4;
  const int g = wid & 3, ks = wid >> 2;
  const size_t n = (size_t)g * 512 + et * 16 + ln;
  const bool isH = (ks >= 2);
  const unsigned short* wr = (isH ? Wh : Wi) + n * EDIM;
  const unsigned short* ap = isH ? hsrc : xsrc;
  const int as = isH ? EDIM : xstr;
  const unsigned short* a0b = ap + (size_t)ln * as;
  const unsigned short* a1b = ap + (size_t)(16 + ln) * as;
  const int k0 = (ks & 1) * 256 + kq * 8;
  floatx4 acc0 = {0.f, 0.f, 0.f, 0.f}, acc1 = {0.f, 0.f, 0.f, 0.f};
  uint4e x0[4], x1[4];
#pragma unroll
  for (int h = 0; h < 2; ++h) {
    const int kb = k0 + h * 128;
    bf16x8 w0 = ld_bf8(wr + kb);
    bf16x8 w1 = ld_bf8(wr + kb + 32);
    bf16x8 w2 = ld_bf8(wr + kb + 64);
    bf16x8 w3 = ld_bf8(wr + kb + 96);
    ld8_llc(a0b + kb, a1b + kb, x0, x1);
    acc0 = mfma16(__builtin_bit_cast(bf16x8, x0[0]), w0, acc0);
    acc1 = mfma16(__builtin_bit_cast(bf16x8, x1[0]), w0, acc1);
    acc0 = mfma16(__builtin_bit_cast(bf16x8, x0[1]), w1, acc0);
    acc1 = mfma16(__builtin_bit_cast(bf16x8, x1[1]), w1, acc1);
    acc0 = mfma16(__builtin_bit_cast(bf16x8, x0[2]), w2, acc0);
    acc1 = mfma16(__builtin_bit_cast(bf16x8, x1[2]), w2, acc1);
    acc0 = mfma16(__builtin_bit_cast(bf16x8, x0[3]), w3, acc0);
    acc1 = mfma16(__builtin_bit_cast(bf16x8, x1[3]), w3, acc1);
  }
  const int base = ((ks * 4 + g) * 2) * 256 + lane;
#pragma unroll
  for (int r = 0; r < 4; ++r) {
    parts[base + r * 64] = acc0[r];
    parts[base + 256 + r * 64] = acc1[r];
  }
}

// combine K-split partials + bias -> sm_gates[g*512 + b*16 + ln]
__device__ void gate_combine(const float* parts, float* gates,
                             const float* bsum, int et, int tid) {
  for (int v = tid; v < 2048; v += NTHR) {
    const int ln = v & 15, b = (v >> 4) & 31, g = v >> 9;
    const int mt = b >> 4, kq = (b >> 2) & 3, r = b & 3;
    const int lane = kq * 16 + ln;
    float s = 0.f;
#pragma unroll
    for (int ks = 0; ks < 4; ++ks)
      s += parts[((ks * 4 + g) * 2 + mt) * 256 + r * 64 + lane];
    gates[v] = s + bsum[g * 512 + et * 16 + ln];
  }
}

// logits tile (16 vocab x 32 b) + per-tile online-softmax partials -> cep (sc1)
__device__ void logits_tile(const unsigned short* w3b, const unsigned short* hbase,
                            const float* b3, const int* dtok, float* cep,
                            int tile, int tid, int step) {
  const int lane = tid & 63, ln = lane & 15, kq = lane >> 4;
  const unsigned short* wrow = w3b + ((size_t)tile * 16 + ln) * EDIM + kq * 8;
  const unsigned short* a0p = hbase + (size_t)ln * EDIM + kq * 8;
  const unsigned short* a1p = a0p + 16 * EDIM;
  floatx4 acc0 = {0.f, 0.f, 0.f, 0.f}, acc1 = {0.f, 0.f, 0.f, 0.f};
  uint4e x0[4], x1[4];
#pragma unroll
  for (int h = 0; h < 4; ++h) {
    const int kb = h * 128;
    bf16x8 w0 = ld_bf8(wrow + kb);
    bf16x8 w1 = ld_bf8(wrow + kb + 32);
    bf16x8 w2 = ld_bf8(wrow + kb + 64);
    bf16x8 w3 = ld_bf8(wrow + kb + 96);
    ld8_llc(a0p + kb, a1p + kb, x0, x1);
    acc0 = mfma16(__builtin_bit_cast(bf16x8, x0[0]), w0, acc0);
    acc1 = mfma16(__builtin_bit_cast(bf16x8, x1[0]), w0, acc1);
    acc0 = mfma16(__builtin_bit_cast(bf16x8, x0[1]), w1, acc0);
    acc1 = mfma16(__builtin_bit_cast(bf16x8, x1[1]), w1, acc1);
    acc0 = mfma16(__builtin_bit_cast(bf16x8, x0[2]), w2, acc0);
    acc1 = mfma16(__builtin_bit_cast(bf16x8, x1[2]), w2, acc1);
    acc0 = mfma16(__builtin_bit_cast(bf16x8, x0[3]), w3, acc0);
    acc1 = mfma16(__builtin_bit_cast(bf16x8, x1[3]), w3, acc1);
  }
  const float bv = b3[tile * 16 + ln];
  const int v = tile * 16 + ln;
#pragma unroll
  for (int mt = 0; mt < 2; ++mt) {
#pragma unroll
    for (int r = 0; r < 4; ++r) {
      const int b = mt * 16 + kq * 4 + r;
      const int ltok = dtok[b * SDD + step + 1];
      const int lab = (ltok > 0) ? ltok - 1 : 0;
      const float lv = (mt ? acc1[r] : acc0[r]) + bv;
      float m = lv, lb = (v == lab) ? lv : -1e30f;
#pragma unroll
      for (int st = 1; st < 16; st <<= 1) m = fmaxf(m, __shfl_xor(m, st, 64));
      float se = __expf(lv - m);
#pragma unroll
      for (int st = 1; st < 16; st <<= 1) se += __shfl_xor(se, st, 64);
#pragma unroll
      for (int st = 1; st < 16; st <<= 1) lb = fmaxf(lb, __shfl_xor(lb, st, 64));
      if (ln == 0) {
        uint4e pk;
        pk.x = __float_as_uint(m); pk.y = __float_as_uint(se);
        pk.z = __float_as_uint(lb); pk.w = 0u;
        st_b128_llc(cep + ((size_t)b * NTILES + tile) * 4, pk);
      }
    }
  }
}

__global__ __launch_bounds__(NTHR) void seq2seq_kernel(Params p) {
  __shared__ float sm_parts[8192];   // 32 KB K-split partials / W2T matvec partials
  __shared__ float sm_gates[2048];
  __shared__ float sm_c[2048];       // c-state [l][b][ln] (enc: l=0 slot only)
  __shared__ float sm_attn[768];     // 0..47 att, 64.. upo_sum, 192..751 A=[ctx|emb]
  const int tid = threadIdx.x, blk = blockIdx.x;
  char* wsb = p.ws;
  int* bar = (int*)wsb;
  float* wce = (float*)(wsb + WCE_OFF);
  float* h3f = (float*)(wsb + H3F_OFF);
  unsigned short* hbf = (unsigned short*)(wsb + HBF_OFF);
  unsigned short* deb = (unsigned short*)(wsb + DEB_OFF);
  float* cws = (float*)(wsb + CWS_OFF);
  unsigned short* upo = (unsigned short*)(wsb + UPO_OFF);
  unsigned short* exb = (unsigned short*)(wsb + EXB_OFF);
  float* cep = (float*)(wsb + CEP_OFF);
  const unsigned short* wi1 = (const unsigned short*)(wsb + WI1_OFF);
  const unsigned short* wh1 = (const unsigned short*)(wsb + WH1_OFF);
  const unsigned short* wi2 = (const unsigned short*)(wsb + WI2_OFF);
  const unsigned short* wh2 = (const unsigned short*)(wsb + WH2_OFF);
  const unsigned short* w3b = (const unsigned short*)(wsb + W3B_OFF);
  const unsigned short* w2t = (const unsigned short*)(wsb + W2T_OFF);
  const float* bs1 = (const float*)(wsb + BS1_OFF);
  const float* bs2 = (const float*)(wsb + BS2_OFF);
  int ph = 0;
  float total_loss = 0.f;  // blk 0 only

  // ================= encoder: wavefront over d = t + li =================
  {
    const int li = blk >> 5, et = blk & 31;
    sm_c[tid] = 0.f; sm_c[tid + 1024] = 0.f;
    int mylen = 0;
    if (tid < 512) mylen = p.elen[tid >> 4];
    __syncthreads();
    for (int d = 0; d < SEQ + NL - 1; ++d) {
      const int t = d - li;
      if (t >= 0 && t < SEQ) {
        const int tp = t & 1, tq = tp ^ 1;
        const unsigned short* xsrc; int xstr;
        if (li == 0) { xsrc = exb + (size_t)t * EDIM; xstr = SEQ * EDIM; }
        else { xsrc = hbf + ((size_t)tp * NL + (li - 1)) * NB * EDIM; xstr = EDIM; }
        const unsigned short* hsrc = hbf + ((size_t)tq * NL + li) * NB * EDIM;
        gemm4g(wi1 + (size_t)li * 2048 * EDIM, wh1 + (size_t)li * 2048 * EDIM,
               xsrc, xstr, hsrc, et, tid, sm_parts);
        __syncthreads();
        gate_combine(sm_parts, sm_gates, bs1 + li * 2048, et, tid);
        __syncthreads();
        if (tid < 512) {
          const int b = tid >> 4, ln = tid & 15, e = et * 16 + ln;
          const bool act = t < mylen;
          const size_t hup = ((size_t)tp * NL + li) * NB * EDIM + (size_t)b * EDIM + e;
          const size_t hdn = ((size_t)tq * NL + li) * NB * EDIM + (size_t)b * EDIM + e;
          unsigned short hnew;
          if (act) {
            const float ig = sigm(sm_gates[tid]);
            const float fg = sigm(sm_gates[512 + tid]);
            const float gg = tanh_f(sm_gates[1024 + tid]);
            const float og = sigm(sm_gates[1536 + tid]);
            const float cn = fg * sm_c[tid] + ig * gg;
            sm_c[tid] = cn;
            const float h = og * tanh_f(cn);
            hnew = f2bf(h);
            if (li == 3) st_b32_llc(h3f + b * EDIM + e, __float_as_uint(h));
          } else {
            hnew = ld_b16_llc(hbf + hdn);
          }
          st_b16_llc(hbf + hup, hnew);
          if (li == 3) st_b16_llc(upo + ((size_t)b * SEQ + t) * EDIM + e,
                                  act ? hnew : (unsigned short)0);
        }
        if (t == SEQ - 1) {  // dump c for decoder handoff (uniform branch)
          __syncthreads();
          if (tid < 512) {
            const int b = tid >> 4, ln = tid & 15;
            st_b32_llc(cws + ((size_t)li * NB + b) * EDIM + et * 16 + ln,
                       __float_as_uint(sm_c[tid]));
          }
        }
      }
      gsync(bar, ++ph);
    }
  }

  // ================= decoder: 47 steps =================
  for (int t = 0; t < SDD - 1; ++t) {
    const int pw = t & 1, pr = pw ^ 1;
    // ---- phase A: attention+de (blocks 0..31) || logits t-1 (blocks 32..127) ----
    if (blk < NB) {
      const int b = blk;
      const int wid = tid >> 6, lane = tid & 63;
      const float* h3r = h3f + b * EDIM + lane * 8;
      float hq[8];
      {
        const uint4e va = ld_b128_llc(h3r);
        const uint4e vb = ld_b128_llc(h3r + 4);
#pragma unroll
        for (int j = 0; j < 4; ++j) {
          hq[j] = __uint_as_float(va[j]);
          hq[4 + j] = __uint_as_float(vb[j]);
        }
      }
      const int tok = p.dtok[b * SDD + t];
      if (tid < EDIM) sm_attn[240 + tid] = p.emb2[(size_t)tok * EDIM + tid];
      for (int s = wid; s < SEQ; s += 16) {
        const unsigned short* up = upo + ((size_t)b * SEQ + s) * EDIM + lane * 8;
        const uint4e uv = *(const uint4e*)up;   // cached: upo stable during decoder
        float dv = 0.f, sv = 0.f;
#pragma unroll
        for (int j = 0; j < 4; ++j) {
          const unsigned int w = uv[j];
          const float lo = __uint_as_float(w << 16);
          const float hi = __uint_as_float(w & 0xffff0000u);
          dv = fmaf(lo, hq[2 * j], dv); sv += lo;
          dv = fmaf(hi, hq[2 * j + 1], dv); sv += hi;
        }
        dv = wred_sum(dv); sv = wred_sum(sv);
        if (lane == 0) { sm_attn[s] = dv; sm_attn[64 + s] = sv; }
      }
      if (t == 0 && tid >= 512) {  // load c handoff into LDS (written once; cached ok)
#pragma unroll
        for (int j = 0; j < 4; ++j) {
          const int v = (tid - 512) * 4 + j;
          const int l = v >> 9, rem = v & 511, b2 = rem >> 4, ln = rem & 15;
          sm_c[v] = cws[((size_t)l * NB + b2) * EDIM + blk * 16 + ln];
        }
      }
      if (t >= 2 && blk == 0 && wid == 8) {  // accumulate loss of step t-2
        float v = (lane < NB) ? __uint_as_float(ld_b32_llc(wce + lane)) : 0.f;
        v = wred_sum(v);
        if (lane == 0) total_loss += v;
      }
      __syncthreads();
      if (wid == 0) {
        float y = -1e30f;
        if (lane < SEQ) {
          y = p.b1[lane];
          const float* w1r = p.W1 + lane * SEQ;
          for (int s = 0; s < SEQ; ++s) y = fmaf(sm_attn[s], w1r[s], y);
        }
        const float m = wred_max(y);
        const float ex = (lane < SEQ) ? __expf(y - m) : 0.f;
        const float S = wred_sum(ex);
        if (lane < SEQ) sm_attn[192 + lane] = (ex / S) * sm_attn[64 + lane];
      }
      __syncthreads();
      // de = A @ W2T (A = [ctx(48)|emb(512)] in sm_attn[192..751]); 4-way k-split
      {
        const int q = tid >> 8, tn = tid & 255, e2 = tn * 2;
        const int kb = q * 140;
        float a0 = (q == 0) ? p.b2[e2] : 0.f;
        float a1 = (q == 0) ? p.b2[e2 + 1] : 0.f;
        for (int k = kb; k < kb + 140; ++k) {
          const float av = sm_attn[192 + k];
          const unsigned int w = *(const unsigned int*)(w2t + (size_t)k * 512 + e2);
          a0 = fmaf(av, __uint_as_float(w << 16), a0);
          a1 = fmaf(av, __uint_as_float(w & 0xffff0000u), a1);
        }
        sm_parts[q * 512 + e2] = a0;
        sm_parts[q * 512 + e2 + 1] = a1;
      }
      __syncthreads();
      if (tid < 512) {
        const float s = sm_parts[tid] + sm_parts[512 + tid] + sm_parts[1024 + tid] + sm_parts[1536 + tid];
        st_b16_llc(deb + b * EDIM + tid, f2bf(s));
      }
    } else if (t >= 1) {
      const int tile = (tid >> 6) * 96 + (blk - 32);
      if (tile < NTILES)
        logits_tile(w3b, hbf + ((size_t)pr * NL + 3) * NB * EDIM,
                    p.b3, p.dtok, cep, tile, tid, t - 1);
    }
    gsync(bar, ++ph);
    // ---- phases G0..G3 ----
    for (int l = 0; l < NL; ++l) {
      if (blk < NB) {
        const unsigned short* xsrc = (l == 0) ? deb : hbf + ((size_t)pw * NL + (l - 1)) * NB * EDIM;
        const unsigned short* hsrc = hbf + ((size_t)pr * NL + l) * NB * EDIM;
        gemm4g(wi2 + (size_t)l * 2048 * EDIM, wh2 + (size_t)l * 2048 * EDIM,
               xsrc, EDIM, hsrc, blk, tid, sm_parts);
        __syncthreads();
        gate_combine(sm_parts, sm_gates, bs2 + l * 2048, blk, tid);
        __syncthreads();
        if (tid < 512) {
          const int b = tid >> 4, ln = tid & 15, e = blk * 16 + ln;
          const float ig = sigm(sm_gates[tid]);
          const float fg = sigm(sm_gates[512 + tid]);
          const float gg = tanh_f(sm_gates[1024 + tid]);
          const float og = sigm(sm_gates[1536 + tid]);
          const float cn = fg * sm_c[l * 512 + tid] + ig * gg;
          sm_c[l * 512 + tid] = cn;
          const float h = og * tanh_f(cn);
          st_b16_llc(hbf + ((size_t)pw * NL + l) * NB * EDIM + (size_t)b * EDIM + e, f2bf(h));
          if (l == 3) st_b32_llc(h3f + b * EDIM + e, __float_as_uint(h));
        }
      } else if (l == 0 && blk >= 32 && blk < 64 && t >= 1) {
        // combine logits partials of step t-1 -> wce[b]
        const int b = blk - 32;
        float m = -1e30f, s = 0.f, lb = -1e30f;
        if (tid < NTILES) {
          const uint4e v = ld_b128_llc(cep + ((size_t)b * NTILES + tid) * 4);
          m = __uint_as_float(v.x); s = __uint_as_float(v.y); lb = __uint_as_float(v.z);
        }
        const int wid = tid >> 6, lane = tid & 63;
        const float M = wred_max(m);
        float sc = s * __expf(m - M);
        sc = wred_sum(sc);
        const float wl = wred_max(lb);
        if (lane == 0) { sm_parts[wid] = M; sm_parts[16 + wid] = sc; sm_parts[32 + wid] = wl; }
        __syncthreads();
        if (tid == 0) {
          float M2 = -1e30f, LB = -1e30f;
          for (int w = 0; w < 16; ++w) M2 = fmaxf(M2, sm_parts[w]);
          float S = 0.f;
          for (int w = 0; w < 16; ++w) S += sm_parts[16 + w] * __expf(sm_parts[w] - M2);
          for (int w = 0; w < 16; ++w) LB = fmaxf(LB, sm_parts[32 + w]);
          const int step = t - 1;
          const int ltok = p.dtok[b * SDD + step + 1];
          int cnt = 0;
          for (int b2 = 0; b2 < NB; ++b2) cnt += (p.dtok[b2 * SDD + step + 1] != 0);
          const float val = (ltok != 0 && cnt > 0) ? (-(LB - M2 - __logf(S))) / (float)cnt : 0.f;
          st_b32_llc(wce + b, __float_as_uint(val));
        }
      }
      gsync(bar, ++ph);
    }
  }

  // ================= tail: logits + CE for step 46 =================
  {
    const int t46 = SDD - 2;  // h parity after step 46 = 0
    if (blk >= 32) {
      const int tile = (tid >> 6) * 96 + (blk - 32);
      if (tile < NTILES)
        logits_tile(w3b, hbf + ((size_t)0 * NL + 3) * NB * EDIM,
                    p.b3, p.dtok, cep, tile, tid, t46);
    } else if (blk == 0 && (tid >> 6) == 8) {  // accumulate loss of step 45
      float v = ((tid & 63) < NB) ? __uint_as_float(ld_b32_llc(wce + (tid & 63))) : 0.f;
      v = wred_sum(v);
      if ((tid & 63) == 0) total_loss += v;
    }
    gsync(bar, ++ph);
    if (blk >= 32 && blk < 64) {
      const int b = blk - 32;
      float m = -1e30f, s = 0.f, lb = -1e30f;
      if (tid < NTILES) {
        const uint4e v = ld_b128_llc(cep + ((size_t)b * NTILES + tid) * 4);
        m = __uint_as_float(v.x); s = __uint_as_float(v.y); lb = __uint_as_float(v.z);
      }
      const int wid = tid >> 6, lane = tid & 63;
      const float M = wred_max(m);
      float sc = s * __expf(m - M);
      sc = wred_sum(sc);
      const float wl = wred_max(lb);
      if (lane == 0) { sm_parts[wid] = M; sm_parts[16 + wid] = sc; sm_parts[32 + wid] = wl; }
      __syncthreads();
      if (tid == 0) {
        float M2 = -1e30f, LB = -1e30f;
        for (int w = 0; w < 16; ++w) M2 = fmaxf(M2, sm_parts[w]);
        float S = 0.f;
        for (int w = 0; w < 16; ++w) S += sm_parts[16 + w] * __expf(sm_parts[w] - M2);
        for (int w = 0; w < 16; ++w) LB = fmaxf(LB, sm_parts[32 + w]);
        const int ltok = p.dtok[b * SDD + t46 + 1];
        int cnt = 0;
        for (int b2 = 0; b2 < NB; ++b2) cnt += (p.dtok[b2 * SDD + t46 + 1] != 0);
        const float val = (ltok != 0 && cnt > 0) ? (-(LB - M2 - __logf(S))) / (float)cnt : 0.f;
        st_b32_llc(wce + b, __float_as_uint(val));
      }
    }
    gsync(bar, ++ph);
    if (blk == 0 && (tid >> 6) == 8) {
      float v = ((tid & 63) < NB) ? __uint_as_float(ld_b32_llc(wce + (tid & 63))) : 0.f;
      v = wred_sum(v);
      if ((tid & 63) == 0) { total_loss += v; p.out[0] = total_loss; }
    }
  }
}

// ---- weight fp32->bf16 conversion, W2 transpose, bias pre-sum, encoder embedding gather ----
__global__ __launch_bounds__(256) void convert_kernel(
    const float* Wih1, const float* Whh1, const float* Wih2, const float* Whh2,
    const float* W3, const float* emb1, const int* etok, const float* W2,
    const float* bih1, const float* bhh1, const float* bih2, const float* bhh2,
    char* wsb) {
  const long NW = (long)NL * 4 * EDIM * EDIM / 4;
  const long NW3 = (long)DVV * EDIM / 4;
  const long NEX = (long)NB * SEQ * EDIM / 4;
  const long NW2T = (long)560 * EDIM / 4;
  const long BF16_TOTAL = 4 * NW + NW3 + NEX + NW2T;
  const long NBS = (long)NL * 4 * EDIM / 4;
  const long total = BF16_TOTAL + 2 * NBS;
  for (long g = (long)blockIdx.x * blockDim.x + threadIdx.x; g < total;
       g += (long)gridDim.x * blockDim.x) {
    if (g >= BF16_TOTAL) {
      long off = g - BF16_TOTAL;
      const float *A, *Bp; float* D;
      if (off < NBS) { A = bih1; Bp = bhh1; D = (float*)(wsb + BS1_OFF); }
      else { off -= NBS; A = bih2; Bp = bhh2; D = (float*)(wsb + BS2_OFF); }
      float4 x = ((const float4*)A)[off];
      const float4 y = ((const float4*)Bp)[off];
      x.x += y.x; x.y += y.y; x.z += y.z; x.w += y.w;
      ((float4*)D)[off] = x;
      continue;
    }
    float4 v;
    unsigned short* dst;
    long off;
    if (g < 4 * NW) {
      const float* src;
      if (g < NW)           { src = Wih1; dst = (unsigned short*)(wsb + WI1_OFF); off = g; }
      else if (g < 2 * NW)  { src = Whh1; dst = (unsigned short*)(wsb + WH1_OFF); off = g - NW; }
      else if (g < 3 * NW)  { src = Wih2; dst = (unsigned short*)(wsb + WI2_OFF); off = g - 2 * NW; }
      else                  { src = Whh2; dst = (unsigned short*)(wsb + WH2_OFF); off = g - 3 * NW; }
      v = *((const float4*)src + off);
    } else if (g < 4 * NW + NW3) {
      off = g - 4 * NW;
      v = *((const float4*)W3 + off);
      dst = (unsigned short*)(wsb + W3B_OFF);
    } else if (g < 4 * NW + NW3 + NEX) {
      const long e4 = g - 4 * NW - NW3;
      const int k4 = (int)(e4 & 127);
      const long bt = e4 >> 7;
      const int tok = etok[bt];
      v = *((const float4*)(emb1 + (size_t)tok * EDIM) + k4);
      dst = (unsigned short*)(wsb + EXB_OFF);
      off = bt * 128 + k4;
    } else {
      off = g - 4 * NW - NW3 - NEX;
      const int e = (int)(off & 127) * 4;
      const int k = (int)(off >> 7);
      v.x = W2[(size_t)(e + 0) * (SEQ + EDIM) + k];
      v.y = W2[(size_t)(e + 1) * (SEQ + EDIM) + k];
      v.z = W2[(size_t)(e + 2) * (SEQ + EDIM) + k];
      v.w = W2[(size_t)(e + 3) * (SEQ + EDIM) + k];
      dst = (unsigned short*)(wsb + W2T_OFF);
    }
    ushort4e o;
    o.x = f2bf(v.x); o.y = f2bf(v.y); o.z = f2bf(v.z); o.w = f2bf(v.w);
    *(ushort4e*)(dst + off * 4) = o;
  }
}

extern "C" void kernel_launch(void* const* d_in, const int* in_sizes, int n_in,
                              void* d_out, int out_size, void* d_ws, size_t ws_size,
                              hipStream_t stream) {
  (void)in_sizes; (void)n_in; (void)out_size; (void)ws_size;
  const int* etok = (const int*)d_in[0];
  const int* elen = (const int*)d_in[1];
  const int* dtok = (const int*)d_in[2];
  const float* emb1 = (const float*)d_in[3];
  const float* emb2 = (const float*)d_in[4];
  const float* Wih1 = (const float*)d_in[5];
  const float* Whh1 = (const float*)d_in[6];
  const float* bih1 = (const float*)d_in[7];
  const float* bhh1 = (const float*)d_in[8];
  const float* W1 = (const float*)d_in[9];
  const float* b1 = (const float*)d_in[10];
  const float* W2 = (const float*)d_in[11];
  const float* b2 = (const float*)d_in[12];
  const float* Wih2 = (const float*)d_in[13];
  const float* Whh2 = (const float*)d_in[14];
  const float* bih2 = (const float*)d_in[15];
  const float* bhh2 = (const float*)d_in[16];
  const float* W3 = (const float*)d_in[17];
  const float* b3 = (const float*)d_in[18];

  hipMemsetAsync(d_ws, 0, ZERO_BYTES, stream);
  hipLaunchKernelGGL(convert_kernel, dim3(4096), dim3(256), 0, stream,
                     Wih1, Whh1, Wih2, Whh2, W3, emb1, etok, W2,
                     bih1, bhh1, bih2, bhh2, (char*)d_ws);

  Params prm;
  prm.etok = etok; prm.elen = elen; prm.dtok = dtok;
  prm.emb2 = emb2;
  prm.W1 = W1; prm.b1 = b1; prm.b2 = b2;
  prm.b3 = b3;
  prm.out = (float*)d_out;
  prm.ws = (char*)d_ws;
  void* args[] = { &prm };
  hipLaunchCooperativeKernel((const void*)seq2seq_kernel, dim3(NBLK), dim3(NTHR), args, 0, stream);
}

// Round 5
// 6055.655 us; speedup vs baseline: 1.0939x; 1.0939x over previous
//
#include <hip/hip_runtime.h>

#define EDIM 512
#define NL 4
#define NB 32
#define SEQ 48
#define SDD 48
#define DVV 16000
#define NBLK 128
#define NTHR 1024
#define NTILES (DVV/16)   // 1000 vocab tiles of 16

// ---- ws layout (byte offsets) ----
#define BAR_OFF 0
#define WCE_OFF 256
#define H3F_OFF 512                                  // [32][512] f32 top-layer h (for attention)
#define HBF_OFF (H3F_OFF + NB*EDIM*4)                // [2][4][32][512] bf16 h (parity-buffered)
#define ZERO_BYTES (HBF_OFF + 2*NL*NB*EDIM*2)        // memset 0 .. here (bar + hbf zeros)
#define DEB_OFF ZERO_BYTES                           // [32][512] bf16 decoder LSTM input
#define CWS_OFF (DEB_OFF + NB*EDIM*2)                // [4][32][512] f32 c handoff enc->dec
#define UPO_OFF (CWS_OFF + (size_t)NL*NB*EDIM*4)     // [32][48][512] bf16 encoder outputs
#define EXB_OFF (UPO_OFF + (size_t)NB*SEQ*EDIM*2)    // [32][48][512] bf16 encoder embeddings
#define CEP_OFF (EXB_OFF + (size_t)NB*SEQ*EDIM*2)    // [32][1000][4] f32 logits partials
#define WI1_OFF (CEP_OFF + (size_t)NB*NTILES*4*4)
#define WH1_OFF (WI1_OFF + (size_t)NL*4*EDIM*EDIM*2)
#define WI2_OFF (WH1_OFF + (size_t)NL*4*EDIM*EDIM*2)
#define WH2_OFF (WI2_OFF + (size_t)NL*4*EDIM*EDIM*2)
#define W3B_OFF (WH2_OFF + (size_t)NL*4*EDIM*EDIM*2)
#define W2T_OFF (W3B_OFF + (size_t)DVV*EDIM*2)       // [560][512] bf16 W2 transposed
#define BS1_OFF (W2T_OFF + (size_t)560*EDIM*2)       // [4][2048] f32 bih1+bhh1
#define BS2_OFF (BS1_OFF + (size_t)NL*4*EDIM*4)      // [4][2048] f32 bih2+bhh2

typedef __bf16 bf16x8 __attribute__((ext_vector_type(8)));
typedef float floatx4 __attribute__((ext_vector_type(4)));
typedef unsigned int uint4e __attribute__((ext_vector_type(4)));
typedef unsigned short ushort4e __attribute__((ext_vector_type(4)));

struct Params {
  const int *etok, *elen, *dtok;
  const float *emb2;
  const float *W1, *b1, *b2;
  const float *b3;
  float* out;
  char* ws;
};

__device__ __forceinline__ float wred_sum(float v) {
#pragma unroll
  for (int i = 32; i > 0; i >>= 1) v += __shfl_xor(v, i, 64);
  return v;
}
__device__ __forceinline__ float wred_max(float v) {
#pragma unroll
  for (int i = 32; i > 0; i >>= 1) v = fmaxf(v, __shfl_xor(v, i, 64));
  return v;
}
__device__ __forceinline__ float sigm(float x) { return 1.f / (1.f + __expf(-x)); }
__device__ __forceinline__ float tanh_f(float x) { return 1.f - 2.f / (__expf(2.f * x) + 1.f); }
__device__ __forceinline__ unsigned short f2bf(float f) {  // RNE fp32->bf16
  unsigned int u = __float_as_uint(f);
  return (unsigned short)((u + 0x7fffu + ((u >> 16) & 1u)) >> 16);
}
__device__ __forceinline__ bf16x8 ld_bf8(const unsigned short* p) {
  return __builtin_bit_cast(bf16x8, *(const uint4e*)p);
}
__device__ __forceinline__ floatx4 mfma16(bf16x8 a, bf16x8 b, floatx4 c) {
  return __builtin_amdgcn_mfma_f32_16x16x32_bf16(a, b, c, 0, 0, 0);
}

// ===== LLC-coherent (bypass L1+L2) access helpers: sc0 sc1 =====
__device__ __forceinline__ uint4e ld_b128_llc(const void* p) {
  uint4e v;
  asm volatile("global_load_dwordx4 %0, %1, off sc0 sc1\n\ts_waitcnt vmcnt(0)"
               : "=&v"(v) : "v"(p) : "memory");
  return v;
}
__device__ __forceinline__ unsigned int ld_b32_llc(const void* p) {
  unsigned int v;
  asm volatile("global_load_dword %0, %1, off sc0 sc1\n\ts_waitcnt vmcnt(0)"
               : "=&v"(v) : "v"(p) : "memory");
  return v;
}
__device__ __forceinline__ unsigned short ld_b16_llc(const void* p) {
  unsigned short v;
  asm volatile("global_load_ushort %0, %1, off sc0 sc1\n\ts_waitcnt vmcnt(0)"
               : "=&v"(v) : "v"(p) : "memory");
  return v;
}
__device__ __forceinline__ void st_b32_llc(void* p, unsigned int v) {
  asm volatile("global_store_dword %0, %1, off sc0 sc1" :: "v"(p), "v"(v) : "memory");
}
__device__ __forceinline__ void st_b16_llc(void* p, unsigned short v) {
  asm volatile("global_store_short %0, %1, off sc0 sc1" :: "v"(p), "v"(v) : "memory");
}
__device__ __forceinline__ void st_b128_llc(void* p, uint4e v) {
  asm volatile("global_store_dwordx4 %0, %1, off sc0 sc1" :: "v"(p), "v"(v) : "memory");
}
// 8 loads (two rows x 4 chunks, 64B chunk stride), ONE waitcnt.
__device__ __forceinline__ void ld8_llc(const void* p0, const void* p1,
                                        uint4e* o0, uint4e* o1) {
  asm volatile(
      "global_load_dwordx4 %0, %8, off sc0 sc1\n\t"
      "global_load_dwordx4 %1, %8, off offset:64 sc0 sc1\n\t"
      "global_load_dwordx4 %2, %8, off offset:128 sc0 sc1\n\t"
      "global_load_dwordx4 %3, %8, off offset:192 sc0 sc1\n\t"
      "global_load_dwordx4 %4, %9, off sc0 sc1\n\t"
      "global_load_dwordx4 %5, %9, off offset:64 sc0 sc1\n\t"
      "global_load_dwordx4 %6, %9, off offset:128 sc0 sc1\n\t"
      "global_load_dwordx4 %7, %9, off offset:192 sc0 sc1\n\t"
      "s_waitcnt vmcnt(0)"
      : "=&v"(o0[0]), "=&v"(o0[1]), "=&v"(o0[2]), "=&v"(o0[3]),
        "=&v"(o1[0]), "=&v"(o1[1]), "=&v"(o1[2]), "=&v"(o1[3])
      : "v"(p0), "v"(p1) : "memory");
}

// grid barrier: fully RELAXED (no release wbl2 tag-walk, no acquire inv).
// Visibility contract: ALL cross-block state moves via sc0/sc1 helpers above
// (coherent at the memory-side LLC); each wave's stores are vmcnt-drained by
// the compiler before s_barrier, so they are LLC-visible before the arrive-add.
// Consumers' sc1 loads issue only after the spin-exit branch resolves.
__device__ __forceinline__ void gsync(int* bar, int ph) {
  __syncthreads();
  if (threadIdx.x == 0) {
    __hip_atomic_fetch_add(&bar[0], 1, __ATOMIC_RELAXED, __HIP_MEMORY_SCOPE_AGENT);
    const int target = ph * NBLK;
    while (__hip_atomic_load(&bar[0], __ATOMIC_RELAXED, __HIP_MEMORY_SCOPE_AGENT) < target)
      __builtin_amdgcn_s_sleep(2);
  }
  __syncthreads();
}

// One 4-gate LSTM GEMM slice. Weights: cached loads (L2-resident, never invalidated).
// x/h state: sc1 batched loads.
__device__ void gemm4g(const unsigned short* Wi, const unsigned short* Wh,
                       const unsigned short* xsrc, int xstr, const unsigned short* hsrc,
                       int et, int tid, float* parts) {
  const int wid = tid >> 6, lane = tid & 63, ln = lane & 15, kq = lane >> 4;
  const int g = wid & 3, ks = wid >> 2;
  const size_t n = (size_t)g * 512 + et * 16 + ln;
  const bool isH = (ks >= 2);
  const unsigned short* wr = (isH ? Wh : Wi) + n * EDIM;
  const unsigned short* ap = isH ? hsrc : xsrc;
  const int as = isH ? EDIM : xstr;
  const unsigned short* a0b = ap + (size_t)ln * as;
  const unsigned short* a1b = ap + (size_t)(16 + ln) * as;
  const int k0 = (ks & 1) * 256 + kq * 8;
  floatx4 acc0 = {0.f, 0.f, 0.f, 0.f}, acc1 = {0.f, 0.f, 0.f, 0.f};
  uint4e x0[4], x1[4];
#pragma unroll
  for (int h = 0; h < 2; ++h) {
    const int kb = k0 + h * 128;
    bf16x8 w0 = ld_bf8(wr + kb);
    bf16x8 w1 = ld_bf8(wr + kb + 32);
    bf16x8 w2 = ld_bf8(wr + kb + 64);
    bf16x8 w3 = ld_bf8(wr + kb + 96);
    ld8_llc(a0b + kb, a1b + kb, x0, x1);
    acc0 = mfma16(__builtin_bit_cast(bf16x8, x0[0]), w0, acc0);
    acc1 = mfma16(__builtin_bit_cast(bf16x8, x1[0]), w0, acc1);
    acc0 = mfma16(__builtin_bit_cast(bf16x8, x0[1]), w1, acc0);
    acc1 = mfma16(__builtin_bit_cast(bf16x8, x1[1]), w1, acc1);
    acc0 = mfma16(__builtin_bit_cast(bf16x8, x0[2]), w2, acc0);
    acc1 = mfma16(__builtin_bit_cast(bf16x8, x1[2]), w2, acc1);
    acc0 = mfma16(__builtin_bit_cast(bf16x8, x0[3]), w3, acc0);
    acc1 = mfma16(__builtin_bit_cast(bf16x8, x1[3]), w3, acc1);
  }
  const int base = ((ks * 4 + g) * 2) * 256 + lane;
#pragma unroll
  for (int r = 0; r < 4; ++r) {
    parts[base + r * 64] = acc0[r];
    parts[base + 256 + r * 64] = acc1[r];
  }
}

// combine K-split partials + bias -> sm_gates[g*512 + b*16 + ln]
__device__ void gate_combine(const float* parts, float* gates,
                             const float* bsum, int et, int tid) {
  for (int v = tid; v < 2048; v += NTHR) {
    const int ln = v & 15, b = (v >> 4) & 31, g = v >> 9;
    const int mt = b >> 4, kq = (b >> 2) & 3, r = b & 3;
    const int lane = kq * 16 + ln;
    float s = 0.f;
#pragma unroll
    for (int ks = 0; ks < 4; ++ks)
      s += parts[((ks * 4 + g) * 2 + mt) * 256 + r * 64 + lane];
    gates[v] = s + bsum[g * 512 + et * 16 + ln];
  }
}

// logits tile (16 vocab x 32 b) + per-tile online-softmax partials -> cep (sc1)
__device__ void logits_tile(const unsigned short* w3b, const unsigned short* hbase,
                            const float* b3, const int* dtok, float* cep,
                            int tile, int tid, int step) {
  const int lane = tid & 63, ln = lane & 15, kq = lane >> 4;
  const unsigned short* wrow = w3b + ((size_t)tile * 16 + ln) * EDIM + kq * 8;
  const unsigned short* a0p = hbase + (size_t)ln * EDIM + kq * 8;
  const unsigned short* a1p = a0p + 16 * EDIM;
  floatx4 acc0 = {0.f, 0.f, 0.f, 0.f}, acc1 = {0.f, 0.f, 0.f, 0.f};
  uint4e x0[4], x1[4];
#pragma unroll
  for (int h = 0; h < 4; ++h) {
    const int kb = h * 128;
    bf16x8 w0 = ld_bf8(wrow + kb);
    bf16x8 w1 = ld_bf8(wrow + kb + 32);
    bf16x8 w2 = ld_bf8(wrow + kb + 64);
    bf16x8 w3 = ld_bf8(wrow + kb + 96);
    ld8_llc(a0p + kb, a1p + kb, x0, x1);
    acc0 = mfma16(__builtin_bit_cast(bf16x8, x0[0]), w0, acc0);
    acc1 = mfma16(__builtin_bit_cast(bf16x8, x1[0]), w0, acc1);
    acc0 = mfma16(__builtin_bit_cast(bf16x8, x0[1]), w1, acc0);
    acc1 = mfma16(__builtin_bit_cast(bf16x8, x1[1]), w1, acc1);
    acc0 = mfma16(__builtin_bit_cast(bf16x8, x0[2]), w2, acc0);
    acc1 = mfma16(__builtin_bit_cast(bf16x8, x1[2]), w2, acc1);
    acc0 = mfma16(__builtin_bit_cast(bf16x8, x0[3]), w3, acc0);
    acc1 = mfma16(__builtin_bit_cast(bf16x8, x1[3]), w3, acc1);
  }
  const float bv = b3[tile * 16 + ln];
  const int v = tile * 16 + ln;
#pragma unroll
  for (int mt = 0; mt < 2; ++mt) {
#pragma unroll
    for (int r = 0; r < 4; ++r) {
      const int b = mt * 16 + kq * 4 + r;
      const int ltok = dtok[b * SDD + step + 1];
      const int lab = (ltok > 0) ? ltok - 1 : 0;
      const float lv = (mt ? acc1[r] : acc0[r]) + bv;
      float m = lv, lb = (v == lab) ? lv : -1e30f;
#pragma unroll
      for (int st = 1; st < 16; st <<= 1) m = fmaxf(m, __shfl_xor(m, st, 64));
      float se = __expf(lv - m);
#pragma unroll
      for (int st = 1; st < 16; st <<= 1) se += __shfl_xor(se, st, 64);
#pragma unroll
      for (int st = 1; st < 16; st <<= 1) lb = fmaxf(lb, __shfl_xor(lb, st, 64));
      if (ln == 0) {
        uint4e pk;
        pk.x = __float_as_uint(m); pk.y = __float_as_uint(se);
        pk.z = __float_as_uint(lb); pk.w = 0u;
        st_b128_llc(cep + ((size_t)b * NTILES + tile) * 4, pk);
      }
    }
  }
}

__global__ __launch_bounds__(NTHR) void seq2seq_kernel(Params p) {
  __shared__ float sm_parts[8192];   // 32 KB K-split partials / W2T matvec partials
  __shared__ float sm_gates[2048];
  __shared__ float sm_c[2048];       // c-state [l][b][ln] (enc: l=0 slot only)
  __shared__ float sm_attn[768];     // 0..47 att, 64.. upo_sum, 192..751 A=[ctx|emb]
  const int tid = threadIdx.x, blk = blockIdx.x;
  char* wsb = p.ws;
  int* bar = (int*)wsb;
  float* wce = (float*)(wsb + WCE_OFF);
  float* h3f = (float*)(wsb + H3F_OFF);
  unsigned short* hbf = (unsigned short*)(wsb + HBF_OFF);
  unsigned short* deb = (unsigned short*)(wsb + DEB_OFF);
  float* cws = (float*)(wsb + CWS_OFF);
  unsigned short* upo = (unsigned short*)(wsb + UPO_OFF);
  unsigned short* exb = (unsigned short*)(wsb + EXB_OFF);
  float* cep = (float*)(wsb + CEP_OFF);
  const unsigned short* wi1 = (const unsigned short*)(wsb + WI1_OFF);
  const unsigned short* wh1 = (const unsigned short*)(wsb + WH1_OFF);
  const unsigned short* wi2 = (const unsigned short*)(wsb + WI2_OFF);
  const unsigned short* wh2 = (const unsigned short*)(wsb + WH2_OFF);
  const unsigned short* w3b = (const unsigned short*)(wsb + W3B_OFF);
  const unsigned short* w2t = (const unsigned short*)(wsb + W2T_OFF);
  const float* bs1 = (const float*)(wsb + BS1_OFF);
  const float* bs2 = (const float*)(wsb + BS2_OFF);
  int ph = 0;
  float total_loss = 0.f;  // blk 0 only

  // ================= encoder: wavefront over d = t + li =================
  {
    const int li = blk >> 5, et = blk & 31;
    sm_c[tid] = 0.f; sm_c[tid + 1024] = 0.f;
    int mylen = 0;
    if (tid < 512) mylen = p.elen[tid >> 4];
    __syncthreads();
    for (int d = 0; d < SEQ + NL - 1; ++d) {
      const int t = d - li;
      if (t >= 0 && t < SEQ) {
        const int tp = t & 1, tq = tp ^ 1;
        const unsigned short* xsrc; int xstr;
        if (li == 0) { xsrc = exb + (size_t)t * EDIM; xstr = SEQ * EDIM; }
        else { xsrc = hbf + ((size_t)tp * NL + (li - 1)) * NB * EDIM; xstr = EDIM; }
        const unsigned short* hsrc = hbf + ((size_t)tq * NL + li) * NB * EDIM;
        gemm4g(wi1 + (size_t)li * 2048 * EDIM, wh1 + (size_t)li * 2048 * EDIM,
               xsrc, xstr, hsrc, et, tid, sm_parts);
        __syncthreads();
        gate_combine(sm_parts, sm_gates, bs1 + li * 2048, et, tid);
        __syncthreads();
        if (tid < 512) {
          const int b = tid >> 4, ln = tid & 15, e = et * 16 + ln;
          const bool act = t < mylen;
          const size_t hup = ((size_t)tp * NL + li) * NB * EDIM + (size_t)b * EDIM + e;
          const size_t hdn = ((size_t)tq * NL + li) * NB * EDIM + (size_t)b * EDIM + e;
          unsigned short hnew;
          if (act) {
            const float ig = sigm(sm_gates[tid]);
            const float fg = sigm(sm_gates[512 + tid]);
            const float gg = tanh_f(sm_gates[1024 + tid]);
            const float og = sigm(sm_gates[1536 + tid]);
            const float cn = fg * sm_c[tid] + ig * gg;
            sm_c[tid] = cn;
            const float h = og * tanh_f(cn);
            hnew = f2bf(h);
            if (li == 3) st_b32_llc(h3f + b * EDIM + e, __float_as_uint(h));
          } else {
            hnew = ld_b16_llc(hbf + hdn);
          }
          st_b16_llc(hbf + hup, hnew);
          if (li == 3) st_b16_llc(upo + ((size_t)b * SEQ + t) * EDIM + e,
                                  act ? hnew : (unsigned short)0);
        }
        if (t == SEQ - 1) {  // dump c for decoder handoff (uniform branch)
          __syncthreads();
          if (tid < 512) {
            const int b = tid >> 4, ln = tid & 15;
            st_b32_llc(cws + ((size_t)li * NB + b) * EDIM + et * 16 + ln,
                       __float_as_uint(sm_c[tid]));
          }
        }
      }
      gsync(bar, ++ph);
    }
  }

  // ================= decoder: 47 steps =================
  for (int t = 0; t < SDD - 1; ++t) {
    const int pw = t & 1, pr = pw ^ 1;
    // ---- phase A: attention+de (blocks 0..31) || logits t-1 (blocks 32..127) ----
    if (blk < NB) {
      const int b = blk;
      const int wid = tid >> 6, lane = tid & 63;
      const float* h3r = h3f + b * EDIM + lane * 8;
      float hq[8];
      {
        const uint4e va = ld_b128_llc(h3r);
        const uint4e vb = ld_b128_llc(h3r + 4);
#pragma unroll
        for (int j = 0; j < 4; ++j) {
          hq[j] = __uint_as_float(va[j]);
          hq[4 + j] = __uint_as_float(vb[j]);
        }
      }
      const int tok = p.dtok[b * SDD + t];
      if (tid < EDIM) sm_attn[240 + tid] = p.emb2[(size_t)tok * EDIM + tid];
      for (int s = wid; s < SEQ; s += 16) {
        const unsigned short* up = upo + ((size_t)b * SEQ + s) * EDIM + lane * 8;
        const uint4e uv = *(const uint4e*)up;   // cached: upo stable during decoder
        float dv = 0.f, sv = 0.f;
#pragma unroll
        for (int j = 0; j < 4; ++j) {
          const unsigned int w = uv[j];
          const float lo = __uint_as_float(w << 16);
          const float hi = __uint_as_float(w & 0xffff0000u);
          dv = fmaf(lo, hq[2 * j], dv); sv += lo;
          dv = fmaf(hi, hq[2 * j + 1], dv); sv += hi;
        }
        dv = wred_sum(dv); sv = wred_sum(sv);
        if (lane == 0) { sm_attn[s] = dv; sm_attn[64 + s] = sv; }
      }
      if (t == 0 && tid >= 512) {  // load c handoff into LDS (written once; cached ok)
#pragma unroll
        for (int j = 0; j < 4; ++j) {
          const int v = (tid - 512) * 4 + j;
          const int l = v >> 9, rem = v & 511, b2 = rem >> 4, ln = rem & 15;
          sm_c[v] = cws[((size_t)l * NB + b2) * EDIM + blk * 16 + ln];
        }
      }
      if (t >= 2 && blk == 0 && wid == 8) {  // accumulate loss of step t-2
        float v = (lane < NB) ? __uint_as_float(ld_b32_llc(wce + lane)) : 0.f;
        v = wred_sum(v);
        if (lane == 0) total_loss += v;
      }
      __syncthreads();
      if (wid == 0) {
        float y = -1e30f;
        if (lane < SEQ) {
          y = p.b1[lane];
          const float* w1r = p.W1 + lane * SEQ;
          for (int s = 0; s < SEQ; ++s) y = fmaf(sm_attn[s], w1r[s], y);
        }
        const float m = wred_max(y);
        const float ex = (lane < SEQ) ? __expf(y - m) : 0.f;
        const float S = wred_sum(ex);
        if (lane < SEQ) sm_attn[192 + lane] = (ex / S) * sm_attn[64 + lane];
      }
      __syncthreads();
      // de = A @ W2T (A = [ctx(48)|emb(512)] in sm_attn[192..751]); 4-way k-split
      {
        const int q = tid >> 8, tn = tid & 255, e2 = tn * 2;
        const int kb = q * 140;
        float a0 = (q == 0) ? p.b2[e2] : 0.f;
        float a1 = (q == 0) ? p.b2[e2 + 1] : 0.f;
        for (int k = kb; k < kb + 140; ++k) {
          const float av = sm_attn[192 + k];
          const unsigned int w = *(const unsigned int*)(w2t + (size_t)k * 512 + e2);
          a0 = fmaf(av, __uint_as_float(w << 16), a0);
          a1 = fmaf(av, __uint_as_float(w & 0xffff0000u), a1);
        }
        sm_parts[q * 512 + e2] = a0;
        sm_parts[q * 512 + e2 + 1] = a1;
      }
      __syncthreads();
      if (tid < 512) {
        const float s = sm_parts[tid] + sm_parts[512 + tid] + sm_parts[1024 + tid] + sm_parts[1536 + tid];
        st_b16_llc(deb + b * EDIM + tid, f2bf(s));
      }
    } else if (t >= 1) {
      const int tile = (tid >> 6) * 96 + (blk - 32);
      if (tile < NTILES)
        logits_tile(w3b, hbf + ((size_t)pr * NL + 3) * NB * EDIM,
                    p.b3, p.dtok, cep, tile, tid, t - 1);
    }
    gsync(bar, ++ph);
    // ---- phases G0..G3 ----
    for (int l = 0; l < NL; ++l) {
      if (blk < NB) {
        const unsigned short* xsrc = (l == 0) ? deb : hbf + ((size_t)pw * NL + (l - 1)) * NB * EDIM;
        const unsigned short* hsrc = hbf + ((size_t)pr * NL + l) * NB * EDIM;
        gemm4g(wi2 + (size_t)l * 2048 * EDIM, wh2 + (size_t)l * 2048 * EDIM,
               xsrc, EDIM, hsrc, blk, tid, sm_parts);
        __syncthreads();
        gate_combine(sm_parts, sm_gates, bs2 + l * 2048, blk, tid);
        __syncthreads();
        if (tid < 512) {
          const int b = tid >> 4, ln = tid & 15, e = blk * 16 + ln;
          const float ig = sigm(sm_gates[tid]);
          const float fg = sigm(sm_gates[512 + tid]);
          const float gg = tanh_f(sm_gates[1024 + tid]);
          const float og = sigm(sm_gates[1536 + tid]);
          const float cn = fg * sm_c[l * 512 + tid] + ig * gg;
          sm_c[l * 512 + tid] = cn;
          const float h = og * tanh_f(cn);
          st_b16_llc(hbf + ((size_t)pw * NL + l) * NB * EDIM + (size_t)b * EDIM + e, f2bf(h));
          if (l == 3) st_b32_llc(h3f + b * EDIM + e, __float_as_uint(h));
        }
      } else if (l == 0 && blk >= 32 && blk < 64 && t >= 1) {
        // combine logits partials of step t-1 -> wce[b]
        const int b = blk - 32;
        float m = -1e30f, s = 0.f, lb = -1e30f;
        if (tid < NTILES) {
          const uint4e v = ld_b128_llc(cep + ((size_t)b * NTILES + tid) * 4);
          m = __uint_as_float(v.x); s = __uint_as_float(v.y); lb = __uint_as_float(v.z);
        }
        const int wid = tid >> 6, lane = tid & 63;
        const float M = wred_max(m);
        float sc = s * __expf(m - M);
        sc = wred_sum(sc);
        const float wl = wred_max(lb);
        if (lane == 0) { sm_parts[wid] = M; sm_parts[16 + wid] = sc; sm_parts[32 + wid] = wl; }
        __syncthreads();
        if (tid == 0) {
          float M2 = -1e30f, LB = -1e30f;
          for (int w = 0; w < 16; ++w) M2 = fmaxf(M2, sm_parts[w]);
          float S = 0.f;
          for (int w = 0; w < 16; ++w) S += sm_parts[16 + w] * __expf(sm_parts[w] - M2);
          for (int w = 0; w < 16; ++w) LB = fmaxf(LB, sm_parts[32 + w]);
          const int step = t - 1;
          const int ltok = p.dtok[b * SDD + step + 1];
          int cnt = 0;
          for (int b2 = 0; b2 < NB; ++b2) cnt += (p.dtok[b2 * SDD + step + 1] != 0);
          const float val = (ltok != 0 && cnt > 0) ? (-(LB - M2 - __logf(S))) / (float)cnt : 0.f;
          st_b32_llc(wce + b, __float_as_uint(val));
        }
      }
      gsync(bar, ++ph);
    }
  }

  // ================= tail: logits + CE for step 46 =================
  {
    const int t46 = SDD - 2;  // h parity after step 46 = 0
    if (blk >= 32) {
      const int tile = (tid >> 6) * 96 + (blk - 32);
      if (tile < NTILES)
        logits_tile(w3b, hbf + ((size_t)0 * NL + 3) * NB * EDIM,
                    p.b3, p.dtok, cep, tile, tid, t46);
    } else if (blk == 0 && (tid >> 6) == 8) {  // accumulate loss of step 45
      float v = ((tid & 63) < NB) ? __uint_as_float(ld_b32_llc(wce + (tid & 63))) : 0.f;
      v = wred_sum(v);
      if ((tid & 63) == 0) total_loss += v;
    }
    gsync(bar, ++ph);
    if (blk >= 32 && blk < 64) {
      const int b = blk - 32;
      float m = -1e30f, s = 0.f, lb = -1e30f;
      if (tid < NTILES) {
        const uint4e v = ld_b128_llc(cep + ((size_t)b * NTILES + tid) * 4);
        m = __uint_as_float(v.x); s = __uint_as_float(v.y); lb = __uint_as_float(v.z);
      }
      const int wid = tid >> 6, lane = tid & 63;
      const float M = wred_max(m);
      float sc = s * __expf(m - M);
      sc = wred_sum(sc);
      const float wl = wred_max(lb);
      if (lane == 0) { sm_parts[wid] = M; sm_parts[16 + wid] = sc; sm_parts[32 + wid] = wl; }
      __syncthreads();
      if (tid == 0) {
        float M2 = -1e30f, LB = -1e30f;
        for (int w = 0; w < 16; ++w) M2 = fmaxf(M2, sm_parts[w]);
        float S = 0.f;
        for (int w = 0; w < 16; ++w) S += sm_parts[16 + w] * __expf(sm_parts[w] - M2);
        for (int w = 0; w < 16; ++w) LB = fmaxf(LB, sm_parts[32 + w]);
        const int ltok = p.dtok[b * SDD + t46 + 1];
        int cnt = 0;
        for (int b2 = 0; b2 < NB; ++b2) cnt += (p.dtok[b2 * SDD + t46 + 1] != 0);
        const float val = (ltok != 0 && cnt > 0) ? (-(LB - M2 - __logf(S))) / (float)cnt : 0.f;
        st_b32_llc(wce + b, __float_as_uint(val));
      }
    }
    gsync(bar, ++ph);
    if (blk == 0 && (tid >> 6) == 8) {
      float v = ((tid & 63) < NB) ? __uint_as_float(ld_b32_llc(wce + (tid & 63))) : 0.f;
      v = wred_sum(v);
      if ((tid & 63) == 0) { total_loss += v; p.out[0] = total_loss; }
    }
  }
}

// ---- weight fp32->bf16 conversion, W2 transpose, bias pre-sum, encoder embedding gather ----
__global__ __launch_bounds__(256) void convert_kernel(
    const float* Wih1, const float* Whh1, const float* Wih2, const float* Whh2,
    const float* W3, const float* emb1, const int* etok, const float* W2,
    const float* bih1, const float* bhh1, const float* bih2, const float* bhh2,
    char* wsb) {
  const long NW = (long)NL * 4 * EDIM * EDIM / 4;
  const long NW3 = (long)DVV * EDIM / 4;
  const long NEX = (long)NB * SEQ * EDIM / 4;
  const long NW2T = (long)560 * EDIM / 4;
  const long BF16_TOTAL = 4 * NW + NW3 + NEX + NW2T;
  const long NBS = (long)NL * 4 * EDIM / 4;
  const long total = BF16_TOTAL + 2 * NBS;
  for (long g = (long)blockIdx.x * blockDim.x + threadIdx.x; g < total;
       g += (long)gridDim.x * blockDim.x) {
    if (g >= BF16_TOTAL) {
      long off = g - BF16_TOTAL;
      const float *A, *Bp; float* D;
      if (off < NBS) { A = bih1; Bp = bhh1; D = (float*)(wsb + BS1_OFF); }
      else { off -= NBS; A = bih2; Bp = bhh2; D = (float*)(wsb + BS2_OFF); }
      float4 x = ((const float4*)A)[off];
      const float4 y = ((const float4*)Bp)[off];
      x.x += y.x; x.y += y.y; x.z += y.z; x.w += y.w;
      ((float4*)D)[off] = x;
      continue;
    }
    float4 v;
    unsigned short* dst;
    long off;
    if (g < 4 * NW) {
      const float* src;
      if (g < NW)           { src = Wih1; dst = (unsigned short*)(wsb + WI1_OFF); off = g; }
      else if (g < 2 * NW)  { src = Whh1; dst = (unsigned short*)(wsb + WH1_OFF); off = g - NW; }
      else if (g < 3 * NW)  { src = Wih2; dst = (unsigned short*)(wsb + WI2_OFF); off = g - 2 * NW; }
      else                  { src = Whh2; dst = (unsigned short*)(wsb + WH2_OFF); off = g - 3 * NW; }
      v = *((const float4*)src + off);
    } else if (g < 4 * NW + NW3) {
      off = g - 4 * NW;
      v = *((const float4*)W3 + off);
      dst = (unsigned short*)(wsb + W3B_OFF);
    } else if (g < 4 * NW + NW3 + NEX) {
      const long e4 = g - 4 * NW - NW3;
      const int k4 = (int)(e4 & 127);
      const long bt = e4 >> 7;
      const int tok = etok[bt];
      v = *((const float4*)(emb1 + (size_t)tok * EDIM) + k4);
      dst = (unsigned short*)(wsb + EXB_OFF);
      off = bt * 128 + k4;
    } else {
      off = g - 4 * NW - NW3 - NEX;
      const int e = (int)(off & 127) * 4;
      const int k = (int)(off >> 7);
      v.x = W2[(size_t)(e + 0) * (SEQ + EDIM) + k];
      v.y = W2[(size_t)(e + 1) * (SEQ + EDIM) + k];
      v.z = W2[(size_t)(e + 2) * (SEQ + EDIM) + k];
      v.w = W2[(size_t)(e + 3) * (SEQ + EDIM) + k];
      dst = (unsigned short*)(wsb + W2T_OFF);
    }
    ushort4e o;
    o.x = f2bf(v.x); o.y = f2bf(v.y); o.z = f2bf(v.z); o.w = f2bf(v.w);
    *(ushort4e*)(dst + off * 4) = o;
  }
}

extern "C" void kernel_launch(void* const* d_in, const int* in_sizes, int n_in,
                              void* d_out, int out_size, void* d_ws, size_t ws_size,
                              hipStream_t stream) {
  (void)in_sizes; (void)n_in; (void)out_size; (void)ws_size;
  const int* etok = (const int*)d_in[0];
  const int* elen = (const int*)d_in[1];
  const int* dtok = (const int*)d_in[2];
  const float* emb1 = (const float*)d_in[3];
  const float* emb2 = (const float*)d_in[4];
  const float* Wih1 = (const float*)d_in[5];
  const float* Whh1 = (const float*)d_in[6];
  const float* bih1 = (const float*)d_in[7];
  const float* bhh1 = (const float*)d_in[8];
  const float* W1 = (const float*)d_in[9];
  const float* b1 = (const float*)d_in[10];
  const float* W2 = (const float*)d_in[11];
  const float* b2 = (const float*)d_in[12];
  const float* Wih2 = (const float*)d_in[13];
  const float* Whh2 = (const float*)d_in[14];
  const float* bih2 = (const float*)d_in[15];
  const float* bhh2 = (const float*)d_in[16];
  const float* W3 = (const float*)d_in[17];
  const float* b3 = (const float*)d_in[18];

  hipMemsetAsync(d_ws, 0, ZERO_BYTES, stream);
  hipLaunchKernelGGL(convert_kernel, dim3(4096), dim3(256), 0, stream,
                     Wih1, Whh1, Wih2, Whh2, W3, emb1, etok, W2,
                     bih1, bhh1, bih2, bhh2, (char*)d_ws);

  Params prm;
  prm.etok = etok; prm.elen = elen; prm.dtok = dtok;
  prm.emb2 = emb2;
  prm.W1 = W1; prm.b1 = b1; prm.b2 = b2;
  prm.b3 = b3;
  prm.out = (float*)d_out;
  prm.ws = (char*)d_ws;
  void* args[] = { &prm };
  hipLaunchCooperativeKernel((const void*)seq2seq_kernel, dim3(NBLK), dim3(NTHR), args, 0, stream);
}